// Round 1
// baseline (234.981 us; speedup 1.0000x reference)
//
#include <hip/hip_runtime.h>

#define EPSF 1e-12f
#define NKNOTS 30
#define NINT 29

typedef float fvec4 __attribute__((ext_vector_type(4)));

// Uniform knots linspace(0,1,30): s = clamp(x*29, 0, 29), idx = min((int)s, 28),
// t = s - idx. Per-interval cubic y = c.x + t*(c.y + t*(c.z + t*c.w)).
// Coefficients in AoS LDS (29 x float4): one ds_read_b128 per eval; 29 entries
// over 8 bank-groups => worst 4-way conflict = 1.58x on an instr that's hidden
// under HBM latency anyway.
//
// KEY CHANGE vs previous version: grid-stride loop with grid capped at 2048
// blocks (8 blocks/CU = 32 waves/CU full occupancy). Previous launch used
// 32768 blocks with ONE float4 per thread -> every block paid the full PCHIP
// setup (global knot/coeff loads, divergent tid<30 math, 2 barriers) for a
// single vector of work; setup was ~half of each block's lifetime. Now setup
// amortizes over ~16 float4s/thread.

__global__ __launch_bounds__(256) void SimpleSpline_kernel(
    const float* __restrict__ x,
    const float* __restrict__ knots,
    const float* __restrict__ coeffs,
    float* __restrict__ out,
    int n)
{
    __shared__ fvec4 cf[NINT];
    __shared__ float dsh[NKNOTS];

    const int tid = threadIdx.x;

    // ---- PCHIP slopes d[tid] (replicates reference math) ----
    if (tid < NKNOTS) {
        float d;
        if (tid == 0) {
            float h0 = knots[1] - knots[0];
            float h1 = knots[2] - knots[1];
            float de0 = (coeffs[1] - coeffs[0]) / (h0 + EPSF);
            float de1 = (coeffs[2] - coeffs[1]) / (h1 + EPSF);
            d = ((2.0f * h0 + h1) * de0 - h0 * de1) / (h0 + h1 + EPSF);
            if (d * de0 <= 0.0f) d = 0.0f;
            if (fabsf(d) > 3.0f * fabsf(de0)) d = 3.0f * de0;
        } else if (tid == NKNOTS - 1) {
            float hN = knots[NKNOTS - 1] - knots[NKNOTS - 2];
            float hM = knots[NKNOTS - 2] - knots[NKNOTS - 3];
            float deN = (coeffs[NKNOTS - 1] - coeffs[NKNOTS - 2]) / (hN + EPSF);
            float deM = (coeffs[NKNOTS - 2] - coeffs[NKNOTS - 3]) / (hM + EPSF);
            d = ((2.0f * hN + hM) * deN - hN * deM) / (hN + hM + EPSF);
            if (d * deN <= 0.0f) d = 0.0f;
            if (fabsf(d) > 3.0f * fabsf(deN)) d = 3.0f * deN;
        } else {
            float hkm1 = knots[tid] - knots[tid - 1];
            float hk   = knots[tid + 1] - knots[tid];
            float dkm1 = (coeffs[tid] - coeffs[tid - 1]) / (hkm1 + EPSF);
            float dk   = (coeffs[tid + 1] - coeffs[tid]) / (hk + EPSF);
            float w1 = 2.0f * hk + hkm1;
            float w2 = hk + 2.0f * hkm1;
            d = 0.0f;
            if (dkm1 * dk > 0.0f)
                d = (w1 + w2) / (w1 / (dkm1 + EPSF) + w2 / (dk + EPSF));
        }
        dsh[tid] = d;
    }
    __syncthreads();

    // ---- per-interval Hermite -> cubic-in-t coefficients (AoS float4) ----
    if (tid < NINT) {
        float h = knots[tid + 1] - knots[tid];
        float safe_h = (fabsf(h) < EPSF) ? 1.0f : h;
        float yk  = coeffs[tid];
        float yk1 = coeffs[tid + 1];
        float sdk  = safe_h * dsh[tid];
        float sdk1 = safe_h * dsh[tid + 1];
        fvec4 c;
        c.x = yk;
        c.y = sdk;
        c.z = 3.0f * (yk1 - yk) - 2.0f * sdk - sdk1;
        c.w = 2.0f * (yk - yk1) + sdk + sdk1;
        cf[tid] = c;
    }
    __syncthreads();

    auto eval1 = [&](float xi) -> float {
        float s = fminf(fmaxf(xi * 29.0f, 0.0f), 29.0f);
        int idx = (int)s;                      // trunc == floor, s >= 0
        idx = idx > (NINT - 1) ? (NINT - 1) : idx;
        float t = s - (float)idx;
        fvec4 c = cf[idx];                     // ds_read_b128
        return fmaf(t, fmaf(t, fmaf(t, c.w, c.z), c.y), c.x);
    };

    const int n4 = n >> 2;
    const int stride = gridDim.x * blockDim.x;
    const fvec4* __restrict__ xv = (const fvec4*)x;
    fvec4* __restrict__ ov = (fvec4*)out;

    for (int i = blockIdx.x * blockDim.x + tid; i < n4; i += stride) {
        fvec4 v = xv[i];
        fvec4 r;
        r.x = eval1(v.x);
        r.y = eval1(v.y);
        r.z = eval1(v.z);
        r.w = eval1(v.w);
        // nt store: out is write-once; keep x L3-resident instead of letting
        // the 128 MiB output evict it (x + out == exactly the 256 MiB L3).
        __builtin_nontemporal_store(r, &ov[i]);
    }

    // scalar tail (n % 4)
    const int rem = n & 3;
    if (rem) {
        const int base = n4 << 2;
        const int g = blockIdx.x * blockDim.x + tid;
        if (g < rem) out[base + g] = eval1(x[base + g]);
    }
}

extern "C" void kernel_launch(void* const* d_in, const int* in_sizes, int n_in,
                              void* d_out, int out_size, void* d_ws, size_t ws_size,
                              hipStream_t stream) {
    const float* x      = (const float*)d_in[0];
    const float* knots  = (const float*)d_in[1];
    const float* coeffs = (const float*)d_in[2];
    float* out = (float*)d_out;
    const int n = in_sizes[0];

    const int block = 256;
    int n4 = n >> 2;
    int blocks = (n4 + block - 1) / block;
    if (blocks > 2048) blocks = 2048;   // 8 blocks/CU x 256 CU: full occupancy,
                                        // grid-stride amortizes PCHIP setup
    if (blocks < 1) blocks = 1;

    SimpleSpline_kernel<<<blocks, block, 0, stream>>>(x, knots, coeffs, out, n);
}